// Round 1
// baseline (223.198 us; speedup 1.0000x reference)
//
#include <hip/hip_runtime.h>
#include <cstdint>
#include <cstddef>

#define BATCH 4
#define NPTS 8192
#define CHUNK 2048
#define BLOCK 256

// ---------------------------------------------------------------------------
// Pass 1: brute-force NN. For each (dir, batch, query): min over db points.
// dir 0: queries = xyz2 (gt), db = xyz1 (pred)   -> dist1/idx1
// dir 1: queries = xyz1 (pred), db = xyz2 (gt)   -> dist2/idx2
// Result combined across db-chunks with atomicMin on packed u64 key:
//   key = (float_bits(dist) << 32) | idx
// dist >= 0 so u64 ordering == (dist, idx) lexicographic; ties -> min idx,
// which matches JAX argmin first-occurrence semantics.
// ---------------------------------------------------------------------------
__global__ void nn_kernel(const float* __restrict__ xyz1,
                          const float* __restrict__ xyz2,
                          unsigned long long* __restrict__ keys) {
    __shared__ float lx[CHUNK];
    __shared__ float ly[CHUNK];
    __shared__ float lz[CHUNK];

    const int tid  = threadIdx.x;
    const int b    = blockIdx.z & 3;
    const int dir  = blockIdx.z >> 2;
    const float* q_ptr = (dir == 0) ? xyz2 : xyz1;
    const float* d_ptr = (dir == 0) ? xyz1 : xyz2;

    const int chunk0 = blockIdx.y * CHUNK;

    // ---- stage db chunk into LDS (SoA), float4 global loads ----
    // chunk floats = CHUNK*3 = 6144; per thread 24 floats = 6 float4 = 8 points
    const float4* g4 = (const float4*)(d_ptr + (size_t)(b * NPTS + chunk0) * 3);
    float v[24];
#pragma unroll
    for (int k = 0; k < 6; ++k) {
        float4 t = g4[tid * 6 + k];
        v[4 * k + 0] = t.x; v[4 * k + 1] = t.y;
        v[4 * k + 2] = t.z; v[4 * k + 3] = t.w;
    }
#pragma unroll
    for (int i = 0; i < 8; ++i) {
        lx[8 * tid + i] = v[3 * i + 0];
        ly[8 * tid + i] = v[3 * i + 1];
        lz[8 * tid + i] = v[3 * i + 2];
    }

    // ---- load this thread's query point ----
    const int q = blockIdx.x * BLOCK + tid;
    const float* qp = q_ptr + (size_t)(b * NPTS + q) * 3;
    const float qx = qp[0], qy = qp[1], qz = qp[2];

    __syncthreads();

    float bd = 3.4e38f;
    int   bj = 0;

    for (int j = 0; j < CHUNK; j += 4) {
        float4 xs = *(const float4*)(lx + j);
        float4 ys = *(const float4*)(ly + j);
        float4 zs = *(const float4*)(lz + j);
        {
            float dx = qx - xs.x, dy = qy - ys.x, dz = qz - zs.x;
            float d = dx * dx + dy * dy + dz * dz;
            if (d < bd) { bd = d; bj = j + 0; }
        }
        {
            float dx = qx - xs.y, dy = qy - ys.y, dz = qz - zs.y;
            float d = dx * dx + dy * dy + dz * dz;
            if (d < bd) { bd = d; bj = j + 1; }
        }
        {
            float dx = qx - xs.z, dy = qy - ys.z, dz = qz - zs.z;
            float d = dx * dx + dy * dy + dz * dz;
            if (d < bd) { bd = d; bj = j + 2; }
        }
        {
            float dx = qx - xs.w, dy = qy - ys.w, dz = qz - zs.w;
            float d = dx * dx + dy * dy + dz * dz;
            if (d < bd) { bd = d; bj = j + 3; }
        }
    }

    unsigned long long key =
        ((unsigned long long)__float_as_uint(bd) << 32) |
        (unsigned int)(chunk0 + bj);
    atomicMin(&keys[((size_t)(dir * BATCH + b)) * NPTS + q], key);
}

// ---------------------------------------------------------------------------
// Pass 2: count how many queries picked each db point.
// ---------------------------------------------------------------------------
__global__ void count_kernel(const unsigned long long* __restrict__ keys,
                             unsigned int* __restrict__ counts) {
    const int lin = blockIdx.x * blockDim.x + threadIdx.x;  // 0..65535
    const int group = lin >> 13;                            // dir*4 + b
    const unsigned int idx = (unsigned int)keys[lin];
    atomicAdd(&counts[(size_t)group * NPTS + idx], 1u);
}

// ---------------------------------------------------------------------------
// Pass 3: per-query loss term, reduced to a single float.
// out = mean_b (loss1 + loss2)/2 = sum over all 65536 terms / 65536
// ---------------------------------------------------------------------------
__global__ void loss_kernel(const float* __restrict__ xyz1,
                            const float* __restrict__ xyz2,
                            const unsigned long long* __restrict__ keys,
                            const unsigned int* __restrict__ counts,
                            float* __restrict__ accum) {
    const int lin = blockIdx.x * blockDim.x + threadIdx.x;  // 0..65535
    const int group = lin >> 13;
    const int q = lin & (NPTS - 1);
    const int b = group & 3;
    const int dir = group >> 2;
    const float* q_ptr = (dir == 0) ? xyz2 : xyz1;
    const float* d_ptr = (dir == 0) ? xyz1 : xyz2;

    const unsigned int idx = (unsigned int)keys[lin];

    const float* qp = q_ptr + (size_t)(b * NPTS + q) * 3;
    const float* pp = d_ptr + (size_t)(b * NPTS + idx) * 3;
    const float dx = qp[0] - pp[0];
    const float dy = qp[1] - pp[1];
    const float dz = qp[2] - pp[2];
    const float d = dx * dx + dy * dy + dz * dz;

    const float c = (float)counts[(size_t)group * NPTS + idx];
    float w;
    if (dir == 0) {
        // weight1 = 1 / max(frac_21 / c + 1e-6, 1), frac_21 = 1
        w = 1.0f / fmaxf(1.0f / c + 1e-6f, 1.0f);
    } else {
        // weight2 = 1 / (ceil(frac_21) * c + 1e-6) = 1 / (c + 1e-6)
        w = 1.0f / (c + 1e-6f);
    }
    float term = 1.0f - expf(-1000.0f * d) * w;

    // wave reduce (64 lanes)
#pragma unroll
    for (int off = 32; off > 0; off >>= 1)
        term += __shfl_down(term, off);
    if ((threadIdx.x & 63) == 0)
        atomicAdd(accum, term * (1.0f / 65536.0f));
}

__global__ void writeout_kernel(const float* __restrict__ accum,
                                float* __restrict__ out) {
    out[0] = accum[0];
}

extern "C" void kernel_launch(void* const* d_in, const int* in_sizes, int n_in,
                              void* d_out, int out_size, void* d_ws, size_t ws_size,
                              hipStream_t stream) {
    const float* xyz1 = (const float*)d_in[0];  // prediction [4,8192,3]
    const float* xyz2 = (const float*)d_in[1];  // ground truth [4,8192,3]
    float* out = (float*)d_out;

    const size_t nkeys   = (size_t)2 * BATCH * NPTS;          // 65536
    unsigned long long* keys = (unsigned long long*)d_ws;      // 512 KB
    unsigned int* counts = (unsigned int*)((char*)d_ws + nkeys * 8);  // 256 KB
    float* accum = (float*)((char*)d_ws + nkeys * 8 + nkeys * 4);

    hipMemsetAsync(keys, 0xFF, nkeys * 8, stream);
    hipMemsetAsync(counts, 0, nkeys * 4 + 4, stream);  // counts + accum

    nn_kernel<<<dim3(NPTS / BLOCK, NPTS / CHUNK, 2 * BATCH), BLOCK, 0, stream>>>(
        xyz1, xyz2, keys);
    count_kernel<<<(int)(nkeys / BLOCK), BLOCK, 0, stream>>>(keys, counts);
    loss_kernel<<<(int)(nkeys / BLOCK), BLOCK, 0, stream>>>(
        xyz1, xyz2, keys, counts, accum);
    writeout_kernel<<<1, 1, 0, stream>>>(accum, out);
}

// Round 2
// 135.630 us; speedup vs baseline: 1.6456x; 1.6456x over previous
//
#include <hip/hip_runtime.h>
#include <cstdint>
#include <cstddef>

#define BATCH 4
#define NPTS 8192
#define CHUNK 2048          // db points per block (NPTS / 4 chunks)
#define BLOCK 256           // threads per block
#define QPT 2               // queries per thread
#define QPB (BLOCK * QPT)   // 512 queries per block

// ---------------------------------------------------------------------------
// Pass 1: brute-force NN, VALU-minimized.
//   s = 0.5*|p|^2 - q.p   (same ordering as d = |q-p|^2; 3 fma per pair)
// Group-of-8 min3 tree, argmin-within-group deferred to after the loop.
// Cross-chunk combine: atomicMin on u64 key = (mono(s) << 32) | idx, where
// mono() is the standard sign-flip map making float ordering == u32 ordering.
// Ties -> min idx == JAX argmin first-occurrence.
// ---------------------------------------------------------------------------
__device__ __forceinline__ unsigned int mono_f32(float f) {
    unsigned int u = __float_as_uint(f);
    return u ^ (unsigned int)(((int)u >> 31) | 0x80000000);
}

__global__ void __launch_bounds__(BLOCK) nn_kernel(
        const float* __restrict__ xyz1,
        const float* __restrict__ xyz2,
        unsigned long long* __restrict__ keys) {
    __shared__ float lx[CHUNK];
    __shared__ float ly[CHUNK];
    __shared__ float lz[CHUNK];
    __shared__ float lh[CHUNK];

    const int tid = threadIdx.x;
    const int b   = blockIdx.z & 3;
    const int dir = blockIdx.z >> 2;
    const float* q_ptr = (dir == 0) ? xyz2 : xyz1;
    const float* d_ptr = (dir == 0) ? xyz1 : xyz2;

    const int chunk0 = blockIdx.y * CHUNK;

    // ---- stage db chunk into LDS (SoA + half-norm), float4 global loads ----
    // CHUNK*3 = 6144 floats; per thread 24 floats = 6 float4 = 8 points
    const float4* g4 = (const float4*)(d_ptr + (size_t)(b * NPTS + chunk0) * 3);
    float v[24];
#pragma unroll
    for (int k = 0; k < 6; ++k) {
        float4 t = g4[tid * 6 + k];
        v[4 * k + 0] = t.x; v[4 * k + 1] = t.y;
        v[4 * k + 2] = t.z; v[4 * k + 3] = t.w;
    }
#pragma unroll
    for (int i = 0; i < 8; ++i) {
        float px = v[3 * i + 0], py = v[3 * i + 1], pz = v[3 * i + 2];
        lx[8 * tid + i] = px;
        ly[8 * tid + i] = py;
        lz[8 * tid + i] = pz;
        lh[8 * tid + i] = 0.5f * (px * px + py * py + pz * pz);
    }

    // ---- this thread's 2 query points ----
    const int q0 = blockIdx.x * QPB + tid;
    const int q1 = q0 + BLOCK;
    const float* qp0 = q_ptr + (size_t)(b * NPTS + q0) * 3;
    const float* qp1 = q_ptr + (size_t)(b * NPTS + q1) * 3;
    const float qx0 = qp0[0], qy0 = qp0[1], qz0 = qp0[2];
    const float qx1 = qp1[0], qy1 = qp1[1], qz1 = qp1[2];

    __syncthreads();

    float bd0 = 3.4e38f, bd1 = 3.4e38f;
    int   bj0 = 0,       bj1 = 0;

    for (int j = 0; j < CHUNK; j += 8) {
        const float4 xa = *(const float4*)(lx + j);
        const float4 xb = *(const float4*)(lx + j + 4);
        const float4 ya = *(const float4*)(ly + j);
        const float4 yb = *(const float4*)(ly + j + 4);
        const float4 za = *(const float4*)(lz + j);
        const float4 zb = *(const float4*)(lz + j + 4);
        const float4 ha = *(const float4*)(lh + j);
        const float4 hb = *(const float4*)(lh + j + 4);

        // ---- query 0: 24 fma + 4 min + cmp/sel ----
        {
            float s0 = fmaf(-qx0, xa.x, ha.x); s0 = fmaf(-qy0, ya.x, s0); s0 = fmaf(-qz0, za.x, s0);
            float s1 = fmaf(-qx0, xa.y, ha.y); s1 = fmaf(-qy0, ya.y, s1); s1 = fmaf(-qz0, za.y, s1);
            float s2 = fmaf(-qx0, xa.z, ha.z); s2 = fmaf(-qy0, ya.z, s2); s2 = fmaf(-qz0, za.z, s2);
            float s3 = fmaf(-qx0, xa.w, ha.w); s3 = fmaf(-qy0, ya.w, s3); s3 = fmaf(-qz0, za.w, s3);
            float s4 = fmaf(-qx0, xb.x, hb.x); s4 = fmaf(-qy0, yb.x, s4); s4 = fmaf(-qz0, zb.x, s4);
            float s5 = fmaf(-qx0, xb.y, hb.y); s5 = fmaf(-qy0, yb.y, s5); s5 = fmaf(-qz0, zb.y, s5);
            float s6 = fmaf(-qx0, xb.z, hb.z); s6 = fmaf(-qy0, yb.z, s6); s6 = fmaf(-qz0, zb.z, s6);
            float s7 = fmaf(-qx0, xb.w, hb.w); s7 = fmaf(-qy0, yb.w, s7); s7 = fmaf(-qz0, zb.w, s7);
            float t0 = fminf(fminf(s0, s1), s2);   // v_min3
            float t1 = fminf(fminf(s3, s4), s5);   // v_min3
            float t2 = fminf(fminf(s6, s7), t0);   // v_min3
            float m  = fminf(t1, t2);
            if (m < bd0) { bd0 = m; bj0 = j; }
        }
        // ---- query 1 ----
        {
            float s0 = fmaf(-qx1, xa.x, ha.x); s0 = fmaf(-qy1, ya.x, s0); s0 = fmaf(-qz1, za.x, s0);
            float s1 = fmaf(-qx1, xa.y, ha.y); s1 = fmaf(-qy1, ya.y, s1); s1 = fmaf(-qz1, za.y, s1);
            float s2 = fmaf(-qx1, xa.z, ha.z); s2 = fmaf(-qy1, ya.z, s2); s2 = fmaf(-qz1, za.z, s2);
            float s3 = fmaf(-qx1, xa.w, ha.w); s3 = fmaf(-qy1, ya.w, s3); s3 = fmaf(-qz1, za.w, s3);
            float s4 = fmaf(-qx1, xb.x, hb.x); s4 = fmaf(-qy1, yb.x, s4); s4 = fmaf(-qz1, zb.x, s4);
            float s5 = fmaf(-qx1, xb.y, hb.y); s5 = fmaf(-qy1, yb.y, s5); s5 = fmaf(-qz1, zb.y, s5);
            float s6 = fmaf(-qx1, xb.z, hb.z); s6 = fmaf(-qy1, yb.z, s6); s6 = fmaf(-qz1, zb.z, s6);
            float s7 = fmaf(-qx1, xb.w, hb.w); s7 = fmaf(-qy1, yb.w, s7); s7 = fmaf(-qz1, zb.w, s7);
            float t0 = fminf(fminf(s0, s1), s2);
            float t1 = fminf(fminf(s3, s4), s5);
            float t2 = fminf(fminf(s6, s7), t0);
            float m  = fminf(t1, t2);
            if (m < bd1) { bd1 = m; bj1 = j; }
        }
    }

    // ---- resolve argmin within winning group of 8 (LDS tile still live) ----
    // Recompute with the identical fmaf sequence -> bit-identical s values.
    int r0 = 7, r1 = 7;
#pragma unroll
    for (int k = 7; k >= 0; --k) {
        {
            float s = fmaf(-qx0, lx[bj0 + k], lh[bj0 + k]);
            s = fmaf(-qy0, ly[bj0 + k], s);
            s = fmaf(-qz0, lz[bj0 + k], s);
            if (s == bd0) r0 = k;
        }
        {
            float s = fmaf(-qx1, lx[bj1 + k], lh[bj1 + k]);
            s = fmaf(-qy1, ly[bj1 + k], s);
            s = fmaf(-qz1, lz[bj1 + k], s);
            if (s == bd1) r1 = k;
        }
    }

    const size_t base = ((size_t)(dir * BATCH + b)) * NPTS;
    unsigned long long key0 =
        ((unsigned long long)mono_f32(bd0) << 32) | (unsigned int)(chunk0 + bj0 + r0);
    unsigned long long key1 =
        ((unsigned long long)mono_f32(bd1) << 32) | (unsigned int)(chunk0 + bj1 + r1);
    atomicMin(&keys[base + q0], key0);
    atomicMin(&keys[base + q1], key1);
}

// ---------------------------------------------------------------------------
// Pass 2: count how many queries picked each db point.
// ---------------------------------------------------------------------------
__global__ void count_kernel(const unsigned long long* __restrict__ keys,
                             unsigned int* __restrict__ counts) {
    const int lin = blockIdx.x * blockDim.x + threadIdx.x;  // 0..65535
    const int group = lin >> 13;                            // dir*4 + b
    const unsigned int idx = (unsigned int)keys[lin];
    atomicAdd(&counts[(size_t)group * NPTS + idx], 1u);
}

// ---------------------------------------------------------------------------
// Pass 3: per-query loss term (exact distance recomputed), single-float sum.
// ---------------------------------------------------------------------------
__global__ void loss_kernel(const float* __restrict__ xyz1,
                            const float* __restrict__ xyz2,
                            const unsigned long long* __restrict__ keys,
                            const unsigned int* __restrict__ counts,
                            float* __restrict__ accum) {
    const int lin = blockIdx.x * blockDim.x + threadIdx.x;  // 0..65535
    const int group = lin >> 13;
    const int q = lin & (NPTS - 1);
    const int b = group & 3;
    const int dir = group >> 2;
    const float* q_ptr = (dir == 0) ? xyz2 : xyz1;
    const float* d_ptr = (dir == 0) ? xyz1 : xyz2;

    const unsigned int idx = (unsigned int)keys[lin];

    const float* qp = q_ptr + (size_t)(b * NPTS + q) * 3;
    const float* pp = d_ptr + (size_t)(b * NPTS + idx) * 3;
    const float dx = qp[0] - pp[0];
    const float dy = qp[1] - pp[1];
    const float dz = qp[2] - pp[2];
    const float d = dx * dx + dy * dy + dz * dz;

    const float c = (float)counts[(size_t)group * NPTS + idx];
    float w;
    if (dir == 0) {
        // weight1 = 1 / max(frac_21 / c + 1e-6, 1), frac_21 = 1
        w = 1.0f / fmaxf(1.0f / c + 1e-6f, 1.0f);
    } else {
        // weight2 = 1 / (ceil(frac_21) * c + 1e-6) = 1 / (c + 1e-6)
        w = 1.0f / (c + 1e-6f);
    }
    float term = 1.0f - expf(-1000.0f * d) * w;

    // wave reduce (64 lanes)
#pragma unroll
    for (int off = 32; off > 0; off >>= 1)
        term += __shfl_down(term, off);
    if ((threadIdx.x & 63) == 0)
        atomicAdd(accum, term * (1.0f / 65536.0f));
}

__global__ void writeout_kernel(const float* __restrict__ accum,
                                float* __restrict__ out) {
    out[0] = accum[0];
}

extern "C" void kernel_launch(void* const* d_in, const int* in_sizes, int n_in,
                              void* d_out, int out_size, void* d_ws, size_t ws_size,
                              hipStream_t stream) {
    const float* xyz1 = (const float*)d_in[0];  // prediction [4,8192,3]
    const float* xyz2 = (const float*)d_in[1];  // ground truth [4,8192,3]
    float* out = (float*)d_out;

    const size_t nkeys = (size_t)2 * BATCH * NPTS;                    // 65536
    unsigned long long* keys = (unsigned long long*)d_ws;             // 512 KB
    unsigned int* counts = (unsigned int*)((char*)d_ws + nkeys * 8);  // 256 KB
    float* accum = (float*)((char*)d_ws + nkeys * 8 + nkeys * 4);

    hipMemsetAsync(keys, 0xFF, nkeys * 8, stream);
    hipMemsetAsync(counts, 0, nkeys * 4 + 4, stream);  // counts + accum

    nn_kernel<<<dim3(NPTS / QPB, NPTS / CHUNK, 2 * BATCH), BLOCK, 0, stream>>>(
        xyz1, xyz2, keys);
    count_kernel<<<(int)(nkeys / BLOCK), BLOCK, 0, stream>>>(keys, counts);
    loss_kernel<<<(int)(nkeys / BLOCK), BLOCK, 0, stream>>>(
        xyz1, xyz2, keys, counts, accum);
    writeout_kernel<<<1, 1, 0, stream>>>(accum, out);
}

// Round 3
// 117.440 us; speedup vs baseline: 1.9005x; 1.1549x over previous
//
#include <hip/hip_runtime.h>
#include <cstdint>
#include <cstddef>

#define BATCH 4
#define NPTS 8192
#define CHUNK 512           // db points per block (NPTS / 16 chunks)
#define BLOCK 256           // threads per block
#define QPT 8               // queries per thread
#define QPB (BLOCK * QPT)   // 2048 queries per block

// ---------------------------------------------------------------------------
// Pass 1: brute-force NN, VALU-minimized.
//   s = 0.5*|p|^2 - q.p   (same ordering as d = |q-p|^2; 3 fma per pair)
// Group-of-8 min3 tree; argmin-within-group resolved after the loop by
// bit-identical recompute. Cross-chunk combine: atomicMin on u64 key
//   key = (mono(s) << 32) | idx     (mono = order-preserving float->u32)
// Ties -> min idx == JAX argmin first-occurrence.
// Side duty (y==0 blocks): zero counts[] and d_out (stream-ordered before
// count_kernel / loss_kernel).
// ---------------------------------------------------------------------------
__device__ __forceinline__ unsigned int mono_f32(float f) {
    unsigned int u = __float_as_uint(f);
    return u ^ (unsigned int)(((int)u >> 31) | 0x80000000);
}

__global__ void __launch_bounds__(BLOCK) nn_kernel(
        const float* __restrict__ xyz1,
        const float* __restrict__ xyz2,
        unsigned long long* __restrict__ keys,
        unsigned int* __restrict__ counts,
        float* __restrict__ out) {
    __shared__ float lx[CHUNK];
    __shared__ float ly[CHUNK];
    __shared__ float lz[CHUNK];
    __shared__ float lh[CHUNK];

    const int tid = threadIdx.x;
    const int b   = blockIdx.z & 3;
    const int dir = blockIdx.z >> 2;
    const float* q_ptr = (dir == 0) ? xyz2 : xyz1;
    const float* d_ptr = (dir == 0) ? xyz1 : xyz2;

    const int chunk0 = blockIdx.y * CHUNK;

    // ---- side duty: zero counts (2*BATCH*NPTS u32) and out[0] ----
    if (blockIdx.y == 0) {
        const int tidg = (blockIdx.z * 4 + blockIdx.x) * BLOCK + tid; // 0..8191
#pragma unroll
        for (int k = 0; k < 8; ++k)
            counts[tidg * 8 + k] = 0u;
        if (tidg == 0) out[0] = 0.0f;
    }

    // ---- stage db chunk into LDS (SoA + half-norm) ----
    // CHUNK*3 = 1536 floats = 384 float4; threads 0..127 load 3 float4 each
    if (tid < 128) {
        const float4* g4 = (const float4*)(d_ptr + (size_t)(b * NPTS + chunk0) * 3);
        float4 t0 = g4[3 * tid + 0];
        float4 t1 = g4[3 * tid + 1];
        float4 t2 = g4[3 * tid + 2];
        float px[4] = {t0.x, t0.w, t1.z, t2.y};
        float py[4] = {t0.y, t1.x, t1.w, t2.z};
        float pz[4] = {t0.z, t1.y, t2.x, t2.w};
#pragma unroll
        for (int i = 0; i < 4; ++i) {
            lx[4 * tid + i] = px[i];
            ly[4 * tid + i] = py[i];
            lz[4 * tid + i] = pz[i];
            lh[4 * tid + i] = 0.5f * (px[i] * px[i] + py[i] * py[i] + pz[i] * pz[i]);
        }
    }

    // ---- this thread's QPT query points (stride BLOCK for coalescing) ----
    const int qbase = blockIdx.x * QPB + tid;
    float qx[QPT], qy[QPT], qz[QPT];
#pragma unroll
    for (int u = 0; u < QPT; ++u) {
        const float* qp = q_ptr + (size_t)(b * NPTS + qbase + u * BLOCK) * 3;
        qx[u] = qp[0]; qy[u] = qp[1]; qz[u] = qp[2];
    }

    __syncthreads();

    float bd[QPT];
    int   bj[QPT];
#pragma unroll
    for (int u = 0; u < QPT; ++u) { bd[u] = 3.4e38f; bj[u] = 0; }

    for (int j = 0; j < CHUNK; j += 8) {
        float px[8], py[8], pz[8], ph[8];
        *(float4*)&px[0] = *(const float4*)(lx + j);
        *(float4*)&px[4] = *(const float4*)(lx + j + 4);
        *(float4*)&py[0] = *(const float4*)(ly + j);
        *(float4*)&py[4] = *(const float4*)(ly + j + 4);
        *(float4*)&pz[0] = *(const float4*)(lz + j);
        *(float4*)&pz[4] = *(const float4*)(lz + j + 4);
        *(float4*)&ph[0] = *(const float4*)(lh + j);
        *(float4*)&ph[4] = *(const float4*)(lh + j + 4);

#pragma unroll
        for (int u = 0; u < QPT; ++u) {
            float s[8];
#pragma unroll
            for (int k = 0; k < 8; ++k) {
                float t = fmaf(-qx[u], px[k], ph[k]);
                t = fmaf(-qy[u], py[k], t);
                s[k] = fmaf(-qz[u], pz[k], t);
            }
            float m0 = fminf(fminf(s[0], s[1]), s[2]);   // v_min3
            float m1 = fminf(fminf(s[3], s[4]), s[5]);   // v_min3
            float m2 = fminf(fminf(s[6], s[7]), m0);     // v_min3
            float m  = fminf(m1, m2);
            if (m < bd[u]) { bd[u] = m; bj[u] = j; }
        }
    }

    // ---- resolve argmin within winning group of 8 (bit-identical recompute),
    //      candidate reload via float4 LDS reads ----
    const size_t base = ((size_t)(dir * BATCH + b)) * NPTS;
#pragma unroll
    for (int u = 0; u < QPT; ++u) {
        float px[8], py[8], pz[8], ph[8];
        *(float4*)&px[0] = *(const float4*)(lx + bj[u]);
        *(float4*)&px[4] = *(const float4*)(lx + bj[u] + 4);
        *(float4*)&py[0] = *(const float4*)(ly + bj[u]);
        *(float4*)&py[4] = *(const float4*)(ly + bj[u] + 4);
        *(float4*)&pz[0] = *(const float4*)(lz + bj[u]);
        *(float4*)&pz[4] = *(const float4*)(lz + bj[u] + 4);
        *(float4*)&ph[0] = *(const float4*)(lh + bj[u]);
        *(float4*)&ph[4] = *(const float4*)(lh + bj[u] + 4);
        int r = 7;
#pragma unroll
        for (int k = 7; k >= 0; --k) {
            float t = fmaf(-qx[u], px[k], ph[k]);
            t = fmaf(-qy[u], py[k], t);
            t = fmaf(-qz[u], pz[k], t);
            if (t == bd[u]) r = k;
        }
        unsigned long long key =
            ((unsigned long long)mono_f32(bd[u]) << 32) |
            (unsigned int)(chunk0 + bj[u] + r);
        atomicMin(&keys[base + qbase + u * BLOCK], key);
    }
}

// ---------------------------------------------------------------------------
// Pass 2: count how many queries picked each db point.
// ---------------------------------------------------------------------------
__global__ void count_kernel(const unsigned long long* __restrict__ keys,
                             unsigned int* __restrict__ counts) {
    const int lin = blockIdx.x * blockDim.x + threadIdx.x;  // 0..65535
    const int group = lin >> 13;                            // dir*4 + b
    const unsigned int idx = (unsigned int)keys[lin];
    atomicAdd(&counts[(size_t)group * NPTS + idx], 1u);
}

// ---------------------------------------------------------------------------
// Pass 3: per-query loss term (exact distance recomputed), block-reduced,
// atomicAdd straight into d_out (zeroed by nn_kernel).
// out = sum over all 65536 terms / 65536
// ---------------------------------------------------------------------------
__global__ void loss_kernel(const float* __restrict__ xyz1,
                            const float* __restrict__ xyz2,
                            const unsigned long long* __restrict__ keys,
                            const unsigned int* __restrict__ counts,
                            float* __restrict__ out) {
    __shared__ float red[4];
    const int lin = blockIdx.x * blockDim.x + threadIdx.x;  // 0..65535
    const int group = lin >> 13;
    const int q = lin & (NPTS - 1);
    const int b = group & 3;
    const int dir = group >> 2;
    const float* q_ptr = (dir == 0) ? xyz2 : xyz1;
    const float* d_ptr = (dir == 0) ? xyz1 : xyz2;

    const unsigned int idx = (unsigned int)keys[lin];

    const float* qp = q_ptr + (size_t)(b * NPTS + q) * 3;
    const float* pp = d_ptr + (size_t)(b * NPTS + idx) * 3;
    const float dx = qp[0] - pp[0];
    const float dy = qp[1] - pp[1];
    const float dz = qp[2] - pp[2];
    const float d = dx * dx + dy * dy + dz * dz;

    const float c = (float)counts[(size_t)group * NPTS + idx];
    float w;
    if (dir == 0) {
        // weight1 = 1 / max(frac_21 / c + 1e-6, 1), frac_21 = 1
        w = 1.0f / fmaxf(1.0f / c + 1e-6f, 1.0f);
    } else {
        // weight2 = 1 / (ceil(frac_21) * c + 1e-6) = 1 / (c + 1e-6)
        w = 1.0f / (c + 1e-6f);
    }
    float term = 1.0f - expf(-1000.0f * d) * w;

    // wave reduce (64 lanes) -> LDS -> one atomic per block
#pragma unroll
    for (int off = 32; off > 0; off >>= 1)
        term += __shfl_down(term, off);
    const int lane = threadIdx.x & 63;
    const int wid  = threadIdx.x >> 6;
    if (lane == 0) red[wid] = term;
    __syncthreads();
    if (threadIdx.x == 0) {
        float t = red[0] + red[1] + red[2] + red[3];
        atomicAdd(out, t * (1.0f / 65536.0f));
    }
}

extern "C" void kernel_launch(void* const* d_in, const int* in_sizes, int n_in,
                              void* d_out, int out_size, void* d_ws, size_t ws_size,
                              hipStream_t stream) {
    const float* xyz1 = (const float*)d_in[0];  // prediction [4,8192,3]
    const float* xyz2 = (const float*)d_in[1];  // ground truth [4,8192,3]
    float* out = (float*)d_out;

    const size_t nkeys = (size_t)2 * BATCH * NPTS;                    // 65536
    unsigned long long* keys = (unsigned long long*)d_ws;             // 512 KB
    unsigned int* counts = (unsigned int*)((char*)d_ws + nkeys * 8);  // 256 KB

    hipMemsetAsync(keys, 0xFF, nkeys * 8, stream);

    nn_kernel<<<dim3(NPTS / QPB, NPTS / CHUNK, 2 * BATCH), BLOCK, 0, stream>>>(
        xyz1, xyz2, keys, counts, out);
    count_kernel<<<(int)(nkeys / BLOCK), BLOCK, 0, stream>>>(keys, counts);
    loss_kernel<<<(int)(nkeys / BLOCK), BLOCK, 0, stream>>>(
        xyz1, xyz2, keys, counts, out);
}